// Round 11
// baseline (244.483 us; speedup 1.0000x reference)
//
#include <hip/hip_runtime.h>
#include <math.h>

#define HIDDEN 1024
#define SEQ 2048

typedef __attribute__((ext_vector_type(8))) short short8;
typedef __attribute__((ext_vector_type(4))) float f32x4;

__device__ __forceinline__ unsigned short f2bf(float x) {
  union { float f; unsigned u; } c; c.f = x;
  unsigned r = c.u + 0x7FFFu + ((c.u >> 16) & 1u);
  return (unsigned short)(r >> 16);
}
__device__ __forceinline__ float bf2f(unsigned short h) {
  union { unsigned u; float f; } c; c.u = ((unsigned)h) << 16;
  return c.f;
}

// raw v_exp_f32 (exp2) without libm edge-case wrapper
__device__ __forceinline__ float fexp2(float x) {
  float r; asm("v_exp_f32 %0, %1" : "=v"(r) : "v"(x)); return r;
}

// pack two f32 -> one reg of 2 bf16 (RNE), lo in low half
__device__ __forceinline__ unsigned cvt_pk_bf16(float lo, float hi) {
  unsigned r;
  asm("v_cvt_pk_bf16_f32 %0, %1, %2" : "=v"(r) : "v"(lo), "v"(hi));
  return r;
}

// async 16B global -> LDS (wave-uniform LDS base; HW scatters lane i to base+16i)
__device__ __forceinline__ void async_copy16(const void* g, void* l) {
  __builtin_amdgcn_global_load_lds(
      (const __attribute__((address_space(1))) unsigned int*)g,
      (__attribute__((address_space(3))) unsigned int*)l, 16, 0, 0);
}

// ---------------------------------------------------------------------------
// All fp32->bf16 converts in ONE dispatch.
// ---------------------------------------------------------------------------
__global__ __launch_bounds__(256) void cvt_all(
    const float* __restrict__ hs, const float* __restrict__ wq,
    const float* __restrict__ wk, const float* __restrict__ wv,
    const float* __restrict__ wo, const float* __restrict__ w1,
    const float* __restrict__ w2,
    unsigned short* __restrict__ hsb, unsigned short* __restrict__ wqb,
    unsigned short* __restrict__ wkb, unsigned short* __restrict__ wvb,
    unsigned short* __restrict__ wob, unsigned short* __restrict__ w1b,
    unsigned short* __restrict__ w2b)
{
  const int i = blockIdx.x * 256 + threadIdx.x;
  const float* src; unsigned short* dst; int off;
  if (i < 1048576)      { src = hs; dst = hsb; off = i; }
  else if (i < 1310720) { src = wq; dst = wqb; off = i - 1048576; }
  else if (i < 1376256) { src = wk; dst = wkb; off = i - 1310720; }
  else if (i < 1441792) { src = wv; dst = wvb; off = i - 1376256; }
  else if (i < 1703936) { src = wo; dst = wob; off = i - 1441792; }
  else if (i < 1966080) { src = w1; dst = w1b; off = i - 1703936; }
  else                  { src = w2; dst = w2b; off = i - 1966080; }
  float4 v = ((const float4*)src)[off];
  ushort4 o;
  o.x = f2bf(v.x); o.y = f2bf(v.y); o.z = f2bf(v.z); o.w = f2bf(v.w);
  ((ushort4*)dst)[off] = o;
}

// ---------------------------------------------------------------------------
// bf16 MFMA GEMM v20 "gemm_sk": SPLIT-K=2 on the proven 64x128 single-
// buffered structure (R7/R8 body). R5-R9 falsified tile-ratio / occupancy /
// barrier-count / intra-wave-ILP (five structures, all 38-45us, pipes <35%).
// Never-varied axis: grid-level parallelism at fixed work (qkv w/ 768 blocks
// = 322 TF vs mains w/ 512 = 215 TF, same structure; m102 curve climbs with
// dispatch size). Each block does HALF of K (8 BK=64 steps); grid 1024 =
// 4 blocks/CU resident (24 KB LDS). Partials bf16, NO bias/relu (folded
// into consumers). XCD chunk = 128 consecutive swz -> one kh, 2 MB L2 set.
// ---------------------------------------------------------------------------
__global__ __launch_bounds__(256) void gemm_sk(
    const unsigned short* __restrict__ A, const unsigned short* __restrict__ W,
    unsigned short* __restrict__ P0, unsigned short* __restrict__ P1,
    int M, int N, int K)
{
  __shared__ unsigned short As[64 * 64];
  __shared__ unsigned short Bs[128 * 64];

  const int flat = blockIdx.x;                       // 0..1023
  const int swz = (flat & 7) * ((int)gridDim.x >> 3) + (flat >> 3);
  const int halfn = (int)gridDim.x >> 1;             // 512
  const int kh = swz >= halfn;
  const int rem = swz & (halfn - 1);
  const int ntx = N >> 7;
  const int m0 = (rem / ntx) * 64, n0 = (rem % ntx) * 128;
  const int kbase = kh * (K >> 1);
  unsigned short* __restrict__ Pd = kh ? P1 : P0;

  const int tid = threadIdx.x;
  const int lane = tid & 63, wave = tid >> 6;
  const int ln = lane & 15, quad = lane >> 4;
  const int wm = (wave >> 1) * 32, wn = (wave & 1) * 64;

  f32x4 acc[2][4];
#pragma unroll
  for (int i = 0; i < 2; ++i)
#pragma unroll
    for (int j = 0; j < 4; ++j) acc[i][j] = (f32x4){0.f, 0.f, 0.f, 0.f};

  const int kend = kbase + (K >> 1);
  for (int k0 = kbase; k0 < kend; k0 += 64) {
#pragma unroll
    for (int it = 0; it < 2; ++it) {
      const int c = (wave * 2 + it) * 64 + lane;
      const int row = c >> 3, gc = (c & 7) ^ (row & 7);
      async_copy16(A + (size_t)(m0 + row) * K + k0 + gc * 8,
                   &As[(wave * 2 + it) * 512]);
    }
#pragma unroll
    for (int it = 0; it < 4; ++it) {
      const int c = (wave * 4 + it) * 64 + lane;
      const int row = c >> 3, gc = (c & 7) ^ (row & 7);
      async_copy16(W + (size_t)(n0 + row) * K + k0 + gc * 8,
                   &Bs[(wave * 4 + it) * 512]);
    }
    __syncthreads();

    short8 af[2][2], bfr[4][2];
#pragma unroll
    for (int i = 0; i < 2; ++i) {
      const int row = wm + i * 16 + ln;
#pragma unroll
      for (int f = 0; f < 2; ++f) {
        const int ch = row * 8 + ((f * 4 + quad) ^ (row & 7));
        af[i][f] = *(const short8*)&As[ch * 8];
      }
    }
#pragma unroll
    for (int j = 0; j < 4; ++j) {
      const int row = wn + j * 16 + ln;
#pragma unroll
      for (int f = 0; f < 2; ++f) {
        const int ch = row * 8 + ((f * 4 + quad) ^ (row & 7));
        bfr[j][f] = *(const short8*)&Bs[ch * 8];
      }
    }
#pragma unroll
    for (int i = 0; i < 2; ++i)
#pragma unroll
      for (int j = 0; j < 4; ++j) {
        acc[i][j] = __builtin_amdgcn_mfma_f32_16x16x32_bf16(af[i][0], bfr[j][0], acc[i][j], 0, 0, 0);
        acc[i][j] = __builtin_amdgcn_mfma_f32_16x16x32_bf16(af[i][1], bfr[j][1], acc[i][j], 0, 0, 0);
      }
    __syncthreads();
  }

#pragma unroll
  for (int j = 0; j < 4; ++j) {
    const int n = n0 + wn + j * 16 + ln;
#pragma unroll
    for (int i = 0; i < 2; ++i) {
#pragma unroll
      for (int rr = 0; rr < 4; ++rr) {
        const int m = m0 + wm + i * 16 + quad * 4 + rr;
        Pd[(size_t)m * N + n] = f2bf(acc[i][j][rr]);
      }
    }
  }
}

// ---------------------------------------------------------------------------
// Combine split-K partials + bias + ReLU -> bf16. (w1 stage)
// ---------------------------------------------------------------------------
__global__ __launch_bounds__(256) void comb_relu(
    const unsigned short* __restrict__ P0, const unsigned short* __restrict__ P1,
    const float* __restrict__ bias, unsigned short* __restrict__ out)
{
  const int i = (blockIdx.x * 256 + threadIdx.x) * 4;
  const int col = i & 1023;
  const ushort4 a = *(const ushort4*)&P0[i];
  const ushort4 b = *(const ushort4*)&P1[i];
  const float4 bv = *(const float4*)&bias[col];
  ushort4 o;
  o.x = f2bf(fmaxf(bf2f(a.x) + bf2f(b.x) + bv.x, 0.f));
  o.y = f2bf(fmaxf(bf2f(a.y) + bf2f(b.y) + bv.y, 0.f));
  o.z = f2bf(fmaxf(bf2f(a.z) + bf2f(b.z) + bv.z, 0.f));
  o.w = f2bf(fmaxf(bf2f(a.w) + bf2f(b.w) + bv.w, 0.f));
  *(ushort4*)&out[i] = o;
}

// ---------------------------------------------------------------------------
// Fused QKV GEMM: 64x128 tile, SINGLE-buffered (24 KB) -> 6 blocks/CU.
// (unchanged; control)
// ---------------------------------------------------------------------------
__global__ __launch_bounds__(256) void gemm_qkv(
    const unsigned short* __restrict__ A,
    const unsigned short* __restrict__ Wq, const unsigned short* __restrict__ Wk,
    const unsigned short* __restrict__ Wv,
    const float* __restrict__ bq, const float* __restrict__ bk,
    const float* __restrict__ bv,
    unsigned short* __restrict__ Qo, unsigned short* __restrict__ Ko,
    unsigned short* __restrict__ Vt)
{
  __shared__ unsigned short As[64 * 64];
  __shared__ unsigned short Bs[128 * 64];

  const int flat = blockIdx.x;                 // 0..767
  const int swz = (flat & 7) * 96 + (flat >> 3);
  const int bx = swz % 12, by = swz / 12;

  int mode, nw0;
  const unsigned short* W;
  const float* bias;
  if (bx < 8)       { mode = 0; W = Wq; bias = bq; nw0 = bx * 128; }
  else if (bx < 10) { mode = 1; W = Wk; bias = bk; nw0 = (bx - 8) * 128; }
  else              { mode = 2; W = Wv; bias = bv; nw0 = (bx - 10) * 128; }

  const int tid = threadIdx.x;
  const int lane = tid & 63, wave = tid >> 6;
  const int ln = lane & 15, quad = lane >> 4;
  const int wm = (wave >> 1) * 32, wn = (wave & 1) * 64;
  const int m0 = by * 64;
  const int K = 1024;

  f32x4 acc[2][4];
#pragma unroll
  for (int i = 0; i < 2; ++i)
#pragma unroll
    for (int j = 0; j < 4; ++j) acc[i][j] = (f32x4){0.f, 0.f, 0.f, 0.f};

  for (int k0 = 0; k0 < K; k0 += 64) {
#pragma unroll
    for (int it = 0; it < 2; ++it) {
      const int c = (wave * 2 + it) * 64 + lane;
      const int row = c >> 3, gc = (c & 7) ^ (row & 7);
      async_copy16(A + (size_t)(m0 + row) * K + k0 + gc * 8,
                   &As[(wave * 2 + it) * 512]);
    }
#pragma unroll
    for (int it = 0; it < 4; ++it) {
      const int c = (wave * 4 + it) * 64 + lane;
      const int row = c >> 3, gc = (c & 7) ^ (row & 7);
      async_copy16(W + (size_t)(nw0 + row) * K + k0 + gc * 8,
                   &Bs[(wave * 4 + it) * 512]);
    }
    __syncthreads();

    short8 af[2][2], bfr[4][2];
#pragma unroll
    for (int i = 0; i < 2; ++i) {
      const int row = wm + i * 16 + ln;
#pragma unroll
      for (int f = 0; f < 2; ++f) {
        const int ch = row * 8 + ((f * 4 + quad) ^ (row & 7));
        af[i][f] = *(const short8*)&As[ch * 8];
      }
    }
#pragma unroll
    for (int j = 0; j < 4; ++j) {
      const int row = wn + j * 16 + ln;
#pragma unroll
      for (int f = 0; f < 2; ++f) {
        const int ch = row * 8 + ((f * 4 + quad) ^ (row & 7));
        bfr[j][f] = *(const short8*)&Bs[ch * 8];
      }
    }
#pragma unroll
    for (int i = 0; i < 2; ++i)
#pragma unroll
      for (int j = 0; j < 4; ++j) {
        acc[i][j] = __builtin_amdgcn_mfma_f32_16x16x32_bf16(af[i][0], bfr[j][0], acc[i][j], 0, 0, 0);
        acc[i][j] = __builtin_amdgcn_mfma_f32_16x16x32_bf16(af[i][1], bfr[j][1], acc[i][j], 0, 0, 0);
      }
    __syncthreads();
  }

#pragma unroll
  for (int j = 0; j < 4; ++j) {
    const int nl = nw0 + wn + j * 16 + ln;
    const float bvv = bias[nl];
#pragma unroll
    for (int i = 0; i < 2; ++i) {
#pragma unroll
      for (int rr = 0; rr < 4; ++rr) {
        const int m = m0 + wm + i * 16 + quad * 4 + rr;
        const float v = acc[i][j][rr] + bvv;
        if (mode == 0) {
          Qo[(size_t)m * 1024 + nl] = f2bf(v);
        } else if (mode == 1) {
          Ko[(size_t)m * 256 + nl] = f2bf(v);
        } else {
          const int b = m >> 11, s = m & 2047;
          Vt[((size_t)b * 256 + nl) * SEQ + s] = f2bf(v);
        }
      }
    }
  }
}

// ---------------------------------------------------------------------------
// MFMA flash attention v15: split-KV, 4 waves x qg=4, 256 thr,
// __launch_bounds__(256,2) -> 2 blocks/CU, 8 waves/CU. Measured 41.5-42us.
// (unchanged from R8)
// ---------------------------------------------------------------------------
__global__ __launch_bounds__(256, 2) void attn_mfma(
    const unsigned short* __restrict__ Q, const unsigned short* __restrict__ Kb,
    const unsigned short* __restrict__ Vt,
    unsigned short* __restrict__ N0, unsigned short* __restrict__ N1,
    float* __restrict__ LS)
{
  __shared__ unsigned short Ks[2][64 * 64];
  __shared__ unsigned short Vs[2][64 * 64];

  // XCD-chunked bijective swizzle over 512 blocks (chunk of 64 = one (b,g))
  const int hwb = blockIdx.x;
  const int swz = (hwb & 7) * 64 + (hwb >> 3);
  const int qblk = swz & 7, half = (swz >> 3) & 1, h = (swz >> 4) & 15, b = swz >> 8;
  const int g = h >> 2;

  unsigned short* __restrict__ numO = half ? N1 : N0;
  float* __restrict__ lsO = LS + half * 65536;

  const int tid = threadIdx.x, lane = tid & 63, wave = tid >> 6;
  const int ln = lane & 15, quad = lane >> 4, q8 = quad * 8;
  const int s0 = qblk * 256;
  const float qscale = 0.125f * 1.44269504f;  // softmax scale * log2(e)

  // swizzle constants
  const int ln7 = ln & 7;
  const int x0 = (quad ^ ln7) * 8;        // K/V chunk offset for cols q8
  const int x1 = ((4 + quad) ^ ln7) * 8;  // for cols 32+q8

  // all-ones bf16 B-frag for MFMA row-sums
  short8 ones;
#pragma unroll
  for (int e = 0; e < 8; ++e) ones[e] = (short)0x3F80;

  // ---- Q B-frags straight from global, pre-scaled (4 q-groups per wave)
  short8 qf[4][2];
#pragma unroll
  for (int qg = 0; qg < 4; ++qg) {
    const unsigned short* qsrc =
        Q + ((size_t)(b * SEQ + s0 + wave * 64 + qg * 16 + ln)) * 1024 + h * 64 + q8;
    qf[qg][0] = *(const short8*)qsrc;
    qf[qg][1] = *(const short8*)(qsrc + 32);
#pragma unroll
    for (int e = 0; e < 8; ++e) {
      qf[qg][0][e] = (short)f2bf(bf2f((unsigned short)qf[qg][0][e]) * qscale);
      qf[qg][1][e] = (short)f2bf(bf2f((unsigned short)qf[qg][1][e]) * qscale);
    }
  }

  // staging: chunk c = (wave*2+it)*64 + lane; LDS row=c>>3; gcc=(c&7)^(row&7)
  const int srow = lane >> 3;
  const int sgcc = (lane & 7) ^ srow;

  auto stage = [&](int t0, int p) {
#pragma unroll
    for (int it = 0; it < 2; ++it) {
      const int row = wave * 16 + it * 8 + srow;
      // sigma: key bit perm {r5,r3,r2,r4,r1,r0} -> QK out slots == PV A-frag
      const int skey = (row & 32) | ((row & 8) << 1) | ((row & 4) << 1) |
                       ((row & 16) >> 2) | (row & 3);
      async_copy16(Kb + (size_t)(b * SEQ + t0 + skey) * 256 + g * 64 + sgcc * 8,
                   &Ks[p][(wave * 2 + it) * 512]);
      async_copy16(Vt + (size_t)(b * 256 + g * 64 + row) * SEQ + t0 + sgcc * 8,
                   &Vs[p][(wave * 2 + it) * 512]);
    }
  };

  f32x4 of[4][4];
  f32x4 ls[4];
#pragma unroll
  for (int qg = 0; qg < 4; ++qg) {
    ls[qg] = (f32x4){0.f, 0.f, 0.f, 0.f};
#pragma unroll
    for (int jd = 0; jd < 4; ++jd) of[qg][jd] = (f32x4){0.f, 0.f, 0.f, 0.f};
  }

  const int tbase = half * 16;          // this half's first KV tile
  stage(tbase * 64, 0);                 // prologue prefetch (4 DMAs/wave)

  for (int tt = 0; tt < 16; ++tt) {
    const int p = tt & 1;
    if (tt < 15) {
      stage((tbase + tt + 1) * 64, p ^ 1);             // 4 new DMAs in flight
      asm volatile("s_waitcnt vmcnt(4)" ::: "memory"); // wait only tile-t DMAs
    } else {
      asm volatile("s_waitcnt vmcnt(0)" ::: "memory");
    }
    __builtin_amdgcn_s_barrier();                      // tile t fully in LDS
    asm volatile("" ::: "memory");

    // ---- QK^T + softmax in two qg-halves (live sc halved: 32 f32 not 64)
    short8 pf[4][2];
#pragma unroll
    for (int hf = 0; hf < 2; ++hf) {
      f32x4 sc[2][4];
#pragma unroll
      for (int jn = 0; jn < 4; ++jn) {
        const int krow = (jn * 16 + ln) * 64;
        const short8 kf0 = *(const short8*)&Ks[p][krow + x0];
        const short8 kf1 = *(const short8*)&Ks[p][krow + x1];
#pragma unroll
        for (int q2 = 0; q2 < 2; ++q2) {
          const int qg = hf * 2 + q2;
          f32x4 z = (f32x4){0.f, 0.f, 0.f, 0.f};
          z = __builtin_amdgcn_mfma_f32_16x16x32_bf16(kf0, qf[qg][0], z, 0, 0, 0);
          z = __builtin_amdgcn_mfma_f32_16x16x32_bf16(kf1, qf[qg][1], z, 0, 0, 0);
          sc[q2][jn] = z;
        }
      }
#pragma unroll
      for (int q2 = 0; q2 < 2; ++q2) {
        const int qg = hf * 2 + q2;
#pragma unroll
        for (int jn = 0; jn < 4; ++jn)
#pragma unroll
          for (int r = 0; r < 4; ++r) sc[q2][jn][r] = fexp2(sc[q2][jn][r]);
#pragma unroll
        for (int F = 0; F < 2; ++F) {
          union { unsigned u[4]; short8 s; } pk;
          pk.u[0] = cvt_pk_bf16(sc[q2][2 * F][0], sc[q2][2 * F][1]);
          pk.u[1] = cvt_pk_bf16(sc[q2][2 * F][2], sc[q2][2 * F][3]);
          pk.u[2] = cvt_pk_bf16(sc[q2][2 * F + 1][0], sc[q2][2 * F + 1][1]);
          pk.u[3] = cvt_pk_bf16(sc[q2][2 * F + 1][2], sc[q2][2 * F + 1][3]);
          pf[qg][F] = pk.s;
        }
        ls[qg] = __builtin_amdgcn_mfma_f32_16x16x32_bf16(pf[qg][0], ones, ls[qg], 0, 0, 0);
        ls[qg] = __builtin_amdgcn_mfma_f32_16x16x32_bf16(pf[qg][1], ones, ls[qg], 0, 0, 0);
      }
    }

    // ---- PV: vf frags shared by all 4 q-groups (natural key order)
#pragma unroll
    for (int jd = 0; jd < 4; ++jd) {
      const int vrow = (jd * 16 + ln) * 64;
      const short8 vf0 = *(const short8*)&Vs[p][vrow + x0];
      const short8 vf1 = *(const short8*)&Vs[p][vrow + x1];
#pragma unroll
      for (int qg = 0; qg < 4; ++qg) {
        of[qg][jd] = __builtin_amdgcn_mfma_f32_16x16x32_bf16(pf[qg][0], vf0, of[qg][jd], 0, 0, 0);
        of[qg][jd] = __builtin_amdgcn_mfma_f32_16x16x32_bf16(pf[qg][1], vf1, of[qg][jd], 0, 0, 0);
      }
    }

    asm volatile("" ::: "memory");
    __builtin_amdgcn_s_barrier();   // all buf-p reads done before t+1 overwrites
    asm volatile("" ::: "memory");
  }

  // ---- UNNORMALIZED packed numerator store + row-sum store
#pragma unroll
  for (int qg = 0; qg < 4; ++qg) {
    const int sbase = s0 + wave * 64 + qg * 16 + quad * 4;
    if (ln == 0) {  // lanes 0,16,32,48: ls for rows quad*4+r
#pragma unroll
      for (int r = 0; r < 4; ++r)
        lsO[(b * 16 + h) * 2048 + sbase + r] = ls[qg][r];
    }
#pragma unroll
    for (int jd = 0; jd < 4; ++jd) {
      const int d = jd * 16 + ln;
      ushort4 ov;
      ov.x = f2bf(of[qg][jd][0]);
      ov.y = f2bf(of[qg][jd][1]);
      ov.z = f2bf(of[qg][jd][2]);
      ov.w = f2bf(of[qg][jd][3]);
      *(ushort4*)&numO[((size_t)b * 1024 + h * 64 + d) * SEQ + sbase] = ov;
    }
  }
}

// ---------------------------------------------------------------------------
// Split-KV reduce: att = (num0 + att{=num1}) / (ls0 + ls1). In-place safe.
// ---------------------------------------------------------------------------
__global__ __launch_bounds__(256) void attn_reduce(
    const unsigned short* __restrict__ N0, unsigned short* att,
    const float* __restrict__ LS)
{
  const int i = (blockIdx.x * 256 + threadIdx.x) * 4;  // flat into [b][1024][2048]
  const int row = i >> 11, s = i & 2047;
  const int h = (row >> 6) & 15, b = row >> 10;
  const int lsi = (b * 16 + h) * 2048 + s;
  const float4 l0 = *(const float4*)&LS[lsi];
  const float4 l1 = *(const float4*)&LS[65536 + lsi];
  const ushort4 a = *(const ushort4*)&N0[i];
  const ushort4 c = *(const ushort4*)&att[i];
  ushort4 o;
  o.x = f2bf((bf2f(a.x) + bf2f(c.x)) / (l0.x + l1.x));
  o.y = f2bf((bf2f(a.y) + bf2f(c.y)) / (l0.y + l1.y));
  o.z = f2bf((bf2f(a.z) + bf2f(c.z)) / (l0.z + l1.z));
  o.w = f2bf((bf2f(a.w) + bf2f(c.w)) / (l0.w + l1.w));
  *(ushort4*)&att[i] = o;
}

// ---------------------------------------------------------------------------
// Residual + LayerNorm. One block per row (1024 cols), 256 thr x 4.
// ---------------------------------------------------------------------------
__device__ __forceinline__ void ln_core(float x[4], const float* gam, const float* bet,
                                        int tid, float out[4]) {
  float s1 = x[0] + x[1] + x[2] + x[3];
  float s2 = x[0] * x[0] + x[1] * x[1] + x[2] * x[2] + x[3] * x[3];
#pragma unroll
  for (int off = 1; off < 64; off <<= 1) {
    s1 += __shfl_xor(s1, off);
    s2 += __shfl_xor(s2, off);
  }
  __shared__ float r1[4], r2[4];
  const int wave = tid >> 6;
  if ((tid & 63) == 0) { r1[wave] = s1; r2[wave] = s2; }
  __syncthreads();
  s1 = r1[0] + r1[1] + r1[2] + r1[3];
  s2 = r2[0] + r2[1] + r2[2] + r2[3];
  const float mu  = s1 * (1.0f / HIDDEN);
  const float var = s2 * (1.0f / HIDDEN) - mu * mu;
  const float inv = rsqrtf(var + 1e-5f);
  float4 gv = *(const float4*)&gam[tid * 4];
  float4 bv = *(const float4*)&bet[tid * 4];
  out[0] = (x[0] - mu) * inv * gv.x + bv.x;
  out[1] = (x[1] - mu) * inv * gv.y + bv.y;
  out[2] = (x[2] - mu) * inv * gv.z + bv.z;
  out[3] = (x[3] - mu) * inv * gv.w + bv.w;
}

// resid_ln1 v20: x = hs + (P0 + P1 + bo)  — split-K combine + bias fused in.
__global__ __launch_bounds__(256) void resid_ln1(
    const float* __restrict__ X,
    const unsigned short* __restrict__ P0, const unsigned short* __restrict__ P1,
    const float* __restrict__ bo,
    const float* __restrict__ gam, const float* __restrict__ bet,
    unsigned short* __restrict__ outb)
{
  const int row = blockIdx.x, tid = threadIdx.x;
  const size_t base = (size_t)row * HIDDEN + tid * 4;
  float4 a = *(const float4*)&X[base];
  ushort4 p = *(const ushort4*)&P0[base];
  ushort4 q = *(const ushort4*)&P1[base];
  float4 bv = *(const float4*)&bo[tid * 4];
  float x[4] = {a.x + bf2f(p.x) + bf2f(q.x) + bv.x,
                a.y + bf2f(p.y) + bf2f(q.y) + bv.y,
                a.z + bf2f(p.z) + bf2f(q.z) + bv.z,
                a.w + bf2f(p.w) + bf2f(q.w) + bv.w};
  float o[4];
  ln_core(x, gam, bet, tid, o);
  ushort4 ov;
  ov.x = f2bf(o[0]); ov.y = f2bf(o[1]); ov.z = f2bf(o[2]); ov.w = f2bf(o[3]);
  *(ushort4*)&outb[base] = ov;
}

// resid_ln2 v20: x = obb + (P0 + P1 + b2) — split-K combine + bias fused in.
__global__ __launch_bounds__(256) void resid_ln2(
    const unsigned short* __restrict__ X,
    const unsigned short* __restrict__ P0, const unsigned short* __restrict__ P1,
    const float* __restrict__ b2,
    const float* __restrict__ gam, const float* __restrict__ bet,
    float* __restrict__ out)
{
  const int row = blockIdx.x, tid = threadIdx.x;
  const size_t base = (size_t)row * HIDDEN + tid * 4;
  ushort4 xv = *(const ushort4*)&X[base];
  ushort4 p = *(const ushort4*)&P0[base];
  ushort4 q = *(const ushort4*)&P1[base];
  float4 bv = *(const float4*)&b2[tid * 4];
  float x[4] = {bf2f(xv.x) + bf2f(p.x) + bf2f(q.x) + bv.x,
                bf2f(xv.y) + bf2f(p.y) + bf2f(q.y) + bv.y,
                bf2f(xv.z) + bf2f(p.z) + bf2f(q.z) + bv.z,
                bf2f(xv.w) + bf2f(p.w) + bf2f(q.w) + bv.w};
  float o[4];
  ln_core(x, gam, bet, tid, o);
  float4 ov; ov.x = o[0]; ov.y = o[1]; ov.z = o[2]; ov.w = o[3];
  *(float4*)&out[base] = ov;
}

// ---------------------------------------------------------------------------
extern "C" void kernel_launch(void* const* d_in, const int* in_sizes, int n_in,
                              void* d_out, int out_size, void* d_ws, size_t ws_size,
                              hipStream_t stream)
{
  (void)in_sizes; (void)n_in; (void)out_size; (void)ws_size;
  const float* hs  = (const float*)d_in[0];
  const float* wq  = (const float*)d_in[1];
  const float* bq  = (const float*)d_in[2];
  const float* wk  = (const float*)d_in[3];
  const float* bk  = (const float*)d_in[4];
  const float* wv  = (const float*)d_in[5];
  const float* bvp = (const float*)d_in[6];
  const float* wo  = (const float*)d_in[7];
  const float* bo  = (const float*)d_in[8];
  const float* lng = (const float*)d_in[9];
  const float* lnb = (const float*)d_in[10];
  const float* w1  = (const float*)d_in[11];
  const float* b1  = (const float*)d_in[12];
  const float* w2  = (const float*)d_in[13];
  const float* b2  = (const float*)d_in[14];
  const float* flg = (const float*)d_in[15];
  const float* flb = (const float*)d_in[16];
  float* out = (float*)d_out;

  unsigned short* w = (unsigned short*)d_ws;
  unsigned short* wqb = w;                    // 1048576  (dead after gemm_qkv -> ls buf)
  unsigned short* wkb = w + 1048576;          //  262144
  unsigned short* wvb = w + 1310720;          //  262144
  unsigned short* wob = w + 1572864;          // 1048576
  unsigned short* w1b = w + 2621440;          // 1048576
  unsigned short* w2b = w + 3670016;          // 1048576
  unsigned short* hsb = w + 4718592;          // 4194304  (num0; reused: f1b)
  unsigned short* qb  = w + 8912896;          // 4194304
  unsigned short* kb  = w + 13107200;         // 1048576
  unsigned short* vt  = w + 14155776;         // 1048576
  unsigned short* att = w + 15204352;         // 4194304  (num1 -> reduced in place; obb)
  unsigned short* pa  = w + 19398656;         // 4194304  split-K partial 0 (bf16)
  unsigned short* pb  = w + 23592960;         // 4194304  split-K partial 1 (bf16)
  unsigned short* f1b = hsb;
  unsigned short* obb = att;
  float* lsbuf = (float*)wqb;                 // 2 x 65536 f32 = 512 KB

  dim3 blk(256);
  cvt_all<<<dim3(8704), blk, 0, stream>>>(hs, wq, wk, wv, wo, w1, w2,
                                          hsb, wqb, wkb, wvb, wob, w1b, w2b);

  gemm_qkv<<<dim3(768), blk, 0, stream>>>(hsb, wqb, wkb, wvb, bq, bk, bvp,
                                          qb, kb, vt);
  attn_mfma<<<dim3(512), blk, 0, stream>>>(qb, kb, vt, hsb, att, lsbuf);
  attn_reduce<<<dim3(4096), blk, 0, stream>>>(hsb, att, lsbuf);

  // wo: split-K partials -> ln1 combines (+bias)
  gemm_sk<<<dim3(1024), blk, 0, stream>>>(att, wob, pa, pb, 4096, 1024, 1024);
  resid_ln1<<<dim3(4096), blk, 0, stream>>>(hs, pa, pb, bo, lng, lnb, obb);

  // w1: split-K partials -> combine + bias + relu
  gemm_sk<<<dim3(1024), blk, 0, stream>>>(obb, w1b, pa, pb, 4096, 1024, 1024);
  comb_relu<<<dim3(4096), blk, 0, stream>>>(pa, pb, b1, f1b);

  // w2: split-K partials -> ln2 combines (+bias)
  gemm_sk<<<dim3(1024), blk, 0, stream>>>(f1b, w2b, pa, pb, 4096, 1024, 1024);
  resid_ln2<<<dim3(4096), blk, 0, stream>>>(obb, pa, pb, b2, flg, flb, out);
}

// Round 12
// 225.996 us; speedup vs baseline: 1.0818x; 1.0818x over previous
//
#include <hip/hip_runtime.h>
#include <math.h>

#define HIDDEN 1024
#define SEQ 2048

typedef __attribute__((ext_vector_type(8))) short short8;
typedef __attribute__((ext_vector_type(4))) float f32x4;

__device__ __forceinline__ unsigned short f2bf(float x) {
  union { float f; unsigned u; } c; c.f = x;
  unsigned r = c.u + 0x7FFFu + ((c.u >> 16) & 1u);
  return (unsigned short)(r >> 16);
}
__device__ __forceinline__ float bf2f(unsigned short h) {
  union { unsigned u; float f; } c; c.u = ((unsigned)h) << 16;
  return c.f;
}

// raw v_exp_f32 (exp2) without libm edge-case wrapper
__device__ __forceinline__ float fexp2(float x) {
  float r; asm("v_exp_f32 %0, %1" : "=v"(r) : "v"(x)); return r;
}

// pack two f32 -> one reg of 2 bf16 (RNE), lo in low half
__device__ __forceinline__ unsigned cvt_pk_bf16(float lo, float hi) {
  unsigned r;
  asm("v_cvt_pk_bf16_f32 %0, %1, %2" : "=v"(r) : "v"(lo), "v"(hi));
  return r;
}

// async 16B global -> LDS (wave-uniform LDS base; HW scatters lane i to base+16i)
__device__ __forceinline__ void async_copy16(const void* g, void* l) {
  __builtin_amdgcn_global_load_lds(
      (const __attribute__((address_space(1))) unsigned int*)g,
      (__attribute__((address_space(3))) unsigned int*)l, 16, 0, 0);
}

// ---------------------------------------------------------------------------
// All fp32->bf16 converts in ONE dispatch.
// ---------------------------------------------------------------------------
__global__ __launch_bounds__(256) void cvt_all(
    const float* __restrict__ hs, const float* __restrict__ wq,
    const float* __restrict__ wk, const float* __restrict__ wv,
    const float* __restrict__ wo, const float* __restrict__ w1,
    const float* __restrict__ w2,
    unsigned short* __restrict__ hsb, unsigned short* __restrict__ wqb,
    unsigned short* __restrict__ wkb, unsigned short* __restrict__ wvb,
    unsigned short* __restrict__ wob, unsigned short* __restrict__ w1b,
    unsigned short* __restrict__ w2b)
{
  const int i = blockIdx.x * 256 + threadIdx.x;
  const float* src; unsigned short* dst; int off;
  if (i < 1048576)      { src = hs; dst = hsb; off = i; }
  else if (i < 1310720) { src = wq; dst = wqb; off = i - 1048576; }
  else if (i < 1376256) { src = wk; dst = wkb; off = i - 1310720; }
  else if (i < 1441792) { src = wv; dst = wvb; off = i - 1376256; }
  else if (i < 1703936) { src = wo; dst = wob; off = i - 1441792; }
  else if (i < 1966080) { src = w1; dst = w1b; off = i - 1703936; }
  else                  { src = w2; dst = w2b; off = i - 1966080; }
  float4 v = ((const float4*)src)[off];
  ushort4 o;
  o.x = f2bf(v.x); o.y = f2bf(v.y); o.z = f2bf(v.z); o.w = f2bf(v.w);
  ((ushort4*)dst)[off] = o;
}

// ---------------------------------------------------------------------------
// bf16 MFMA GEMM "gemm_wn BK=128" (R8 best): 64x128 tile, stage both 64-col
// halves before ONE barrier pair, 2 MFMA sub-steps per barrier -> 8 outer
// steps. LDS 48 KB -> 3 blocks/CU. Six falsified theories (tile-ratio,
// occupancy, barrier count, intra-wave ILP, split-K) pin this family at
// ~38-45us for this dispatch size — consistent with the m97-family shape
// curve (8.6 GF -> ~215 TF). XCD-chunked swizzle.
// ---------------------------------------------------------------------------
template<bool RELU>
__global__ __launch_bounds__(256, 3) void gemm_wn(
    const unsigned short* __restrict__ A, const unsigned short* __restrict__ W,
    const float* __restrict__ bias, unsigned short* __restrict__ C,
    int M, int N, int K)
{
  __shared__ unsigned short As[2][64 * 64];
  __shared__ unsigned short Bs[2][128 * 64];

  const int flat = blockIdx.x;
  const int swz = (flat & 7) * ((int)gridDim.x >> 3) + (flat >> 3);
  const int ntx = N >> 7;
  const int m0 = (swz / ntx) * 64, n0 = (swz % ntx) * 128;

  const int tid = threadIdx.x;
  const int lane = tid & 63, wave = tid >> 6;
  const int ln = lane & 15, quad = lane >> 4;
  const int wm = (wave >> 1) * 32, wn = (wave & 1) * 64;

  f32x4 acc[2][4];
#pragma unroll
  for (int i = 0; i < 2; ++i)
#pragma unroll
    for (int j = 0; j < 4; ++j) acc[i][j] = (f32x4){0.f, 0.f, 0.f, 0.f};

  for (int k0 = 0; k0 < K; k0 += 128) {
#pragma unroll
    for (int half = 0; half < 2; ++half) {
      const int kh = k0 + half * 64;
#pragma unroll
      for (int it = 0; it < 2; ++it) {
        const int c = (wave * 2 + it) * 64 + lane;
        const int row = c >> 3, gc = (c & 7) ^ (row & 7);
        async_copy16(A + (size_t)(m0 + row) * K + kh + gc * 8,
                     &As[half][(wave * 2 + it) * 512]);
      }
#pragma unroll
      for (int it = 0; it < 4; ++it) {
        const int c = (wave * 4 + it) * 64 + lane;
        const int row = c >> 3, gc = (c & 7) ^ (row & 7);
        async_copy16(W + (size_t)(n0 + row) * K + kh + gc * 8,
                     &Bs[half][(wave * 4 + it) * 512]);
      }
    }
    __syncthreads();   // one drain per 128 k

#pragma unroll
    for (int half = 0; half < 2; ++half) {
      short8 af[2][2], bfr[4][2];
#pragma unroll
      for (int i = 0; i < 2; ++i) {
        const int row = wm + i * 16 + ln;
#pragma unroll
        for (int f = 0; f < 2; ++f) {
          const int ch = row * 8 + ((f * 4 + quad) ^ (row & 7));
          af[i][f] = *(const short8*)&As[half][ch * 8];
        }
      }
#pragma unroll
      for (int j = 0; j < 4; ++j) {
        const int row = wn + j * 16 + ln;
#pragma unroll
        for (int f = 0; f < 2; ++f) {
          const int ch = row * 8 + ((f * 4 + quad) ^ (row & 7));
          bfr[j][f] = *(const short8*)&Bs[half][ch * 8];
        }
      }
#pragma unroll
      for (int i = 0; i < 2; ++i)
#pragma unroll
        for (int j = 0; j < 4; ++j) {
          acc[i][j] = __builtin_amdgcn_mfma_f32_16x16x32_bf16(af[i][0], bfr[j][0], acc[i][j], 0, 0, 0);
          acc[i][j] = __builtin_amdgcn_mfma_f32_16x16x32_bf16(af[i][1], bfr[j][1], acc[i][j], 0, 0, 0);
        }
    }
    __syncthreads();   // all reads done before next stage overwrites
  }

#pragma unroll
  for (int j = 0; j < 4; ++j) {
    const int n = n0 + wn + j * 16 + ln;
    const float bv = bias[n];
#pragma unroll
    for (int i = 0; i < 2; ++i) {
#pragma unroll
      for (int rr = 0; rr < 4; ++rr) {
        const int m = m0 + wm + i * 16 + quad * 4 + rr;
        float v = acc[i][j][rr] + bv;
        if (RELU) v = fmaxf(v, 0.f);
        C[(size_t)m * N + n] = f2bf(v);
      }
    }
  }
}

// ---------------------------------------------------------------------------
// Fused QKV GEMM: 64x128 tile, SINGLE-buffered (24 KB) -> 6 blocks/CU.
// ---------------------------------------------------------------------------
__global__ __launch_bounds__(256) void gemm_qkv(
    const unsigned short* __restrict__ A,
    const unsigned short* __restrict__ Wq, const unsigned short* __restrict__ Wk,
    const unsigned short* __restrict__ Wv,
    const float* __restrict__ bq, const float* __restrict__ bk,
    const float* __restrict__ bv,
    unsigned short* __restrict__ Qo, unsigned short* __restrict__ Ko,
    unsigned short* __restrict__ Vt)
{
  __shared__ unsigned short As[64 * 64];
  __shared__ unsigned short Bs[128 * 64];

  const int flat = blockIdx.x;                 // 0..767
  const int swz = (flat & 7) * 96 + (flat >> 3);
  const int bx = swz % 12, by = swz / 12;

  int mode, nw0;
  const unsigned short* W;
  const float* bias;
  if (bx < 8)       { mode = 0; W = Wq; bias = bq; nw0 = bx * 128; }
  else if (bx < 10) { mode = 1; W = Wk; bias = bk; nw0 = (bx - 8) * 128; }
  else              { mode = 2; W = Wv; bias = bv; nw0 = (bx - 10) * 128; }

  const int tid = threadIdx.x;
  const int lane = tid & 63, wave = tid >> 6;
  const int ln = lane & 15, quad = lane >> 4;
  const int wm = (wave >> 1) * 32, wn = (wave & 1) * 64;
  const int m0 = by * 64;
  const int K = 1024;

  f32x4 acc[2][4];
#pragma unroll
  for (int i = 0; i < 2; ++i)
#pragma unroll
    for (int j = 0; j < 4; ++j) acc[i][j] = (f32x4){0.f, 0.f, 0.f, 0.f};

  for (int k0 = 0; k0 < K; k0 += 64) {
#pragma unroll
    for (int it = 0; it < 2; ++it) {
      const int c = (wave * 2 + it) * 64 + lane;
      const int row = c >> 3, gc = (c & 7) ^ (row & 7);
      async_copy16(A + (size_t)(m0 + row) * K + k0 + gc * 8,
                   &As[(wave * 2 + it) * 512]);
    }
#pragma unroll
    for (int it = 0; it < 4; ++it) {
      const int c = (wave * 4 + it) * 64 + lane;
      const int row = c >> 3, gc = (c & 7) ^ (row & 7);
      async_copy16(W + (size_t)(nw0 + row) * K + k0 + gc * 8,
                   &Bs[(wave * 4 + it) * 512]);
    }
    __syncthreads();

    short8 af[2][2], bfr[4][2];
#pragma unroll
    for (int i = 0; i < 2; ++i) {
      const int row = wm + i * 16 + ln;
#pragma unroll
      for (int f = 0; f < 2; ++f) {
        const int ch = row * 8 + ((f * 4 + quad) ^ (row & 7));
        af[i][f] = *(const short8*)&As[ch * 8];
      }
    }
#pragma unroll
    for (int j = 0; j < 4; ++j) {
      const int row = wn + j * 16 + ln;
#pragma unroll
      for (int f = 0; f < 2; ++f) {
        const int ch = row * 8 + ((f * 4 + quad) ^ (row & 7));
        bfr[j][f] = *(const short8*)&Bs[ch * 8];
      }
    }
#pragma unroll
    for (int i = 0; i < 2; ++i)
#pragma unroll
      for (int j = 0; j < 4; ++j) {
        acc[i][j] = __builtin_amdgcn_mfma_f32_16x16x32_bf16(af[i][0], bfr[j][0], acc[i][j], 0, 0, 0);
        acc[i][j] = __builtin_amdgcn_mfma_f32_16x16x32_bf16(af[i][1], bfr[j][1], acc[i][j], 0, 0, 0);
      }
    __syncthreads();
  }

#pragma unroll
  for (int j = 0; j < 4; ++j) {
    const int nl = nw0 + wn + j * 16 + ln;
    const float bvv = bias[nl];
#pragma unroll
    for (int i = 0; i < 2; ++i) {
#pragma unroll
      for (int rr = 0; rr < 4; ++rr) {
        const int m = m0 + wm + i * 16 + quad * 4 + rr;
        const float v = acc[i][j][rr] + bvv;
        if (mode == 0) {
          Qo[(size_t)m * 1024 + nl] = f2bf(v);
        } else if (mode == 1) {
          Ko[(size_t)m * 256 + nl] = f2bf(v);
        } else {
          const int b = m >> 11, s = m & 2047;
          Vt[((size_t)b * 256 + nl) * SEQ + s] = f2bf(v);
        }
      }
    }
  }
}

// ---------------------------------------------------------------------------
// MFMA flash attention v15: split-KV, 4 waves x qg=4, 256 thr,
// __launch_bounds__(256,2) -> 2 blocks/CU, 8 waves/CU. Measured 41.5-42us.
// Softmax in two qg-halves to cap live VGPRs. sigma key-perm in-register P
// (conflicts=0), dbuf K/V 32 KB, vmcnt(4), XCD chunk = one (b,g).
// ---------------------------------------------------------------------------
__global__ __launch_bounds__(256, 2) void attn_mfma(
    const unsigned short* __restrict__ Q, const unsigned short* __restrict__ Kb,
    const unsigned short* __restrict__ Vt,
    unsigned short* __restrict__ N0, unsigned short* __restrict__ N1,
    float* __restrict__ LS)
{
  __shared__ unsigned short Ks[2][64 * 64];
  __shared__ unsigned short Vs[2][64 * 64];

  // XCD-chunked bijective swizzle over 512 blocks (chunk of 64 = one (b,g))
  const int hwb = blockIdx.x;
  const int swz = (hwb & 7) * 64 + (hwb >> 3);
  const int qblk = swz & 7, half = (swz >> 3) & 1, h = (swz >> 4) & 15, b = swz >> 8;
  const int g = h >> 2;

  unsigned short* __restrict__ numO = half ? N1 : N0;
  float* __restrict__ lsO = LS + half * 65536;

  const int tid = threadIdx.x, lane = tid & 63, wave = tid >> 6;
  const int ln = lane & 15, quad = lane >> 4, q8 = quad * 8;
  const int s0 = qblk * 256;
  const float qscale = 0.125f * 1.44269504f;  // softmax scale * log2(e)

  // swizzle constants
  const int ln7 = ln & 7;
  const int x0 = (quad ^ ln7) * 8;        // K/V chunk offset for cols q8
  const int x1 = ((4 + quad) ^ ln7) * 8;  // for cols 32+q8

  // all-ones bf16 B-frag for MFMA row-sums
  short8 ones;
#pragma unroll
  for (int e = 0; e < 8; ++e) ones[e] = (short)0x3F80;

  // ---- Q B-frags straight from global, pre-scaled (4 q-groups per wave)
  short8 qf[4][2];
#pragma unroll
  for (int qg = 0; qg < 4; ++qg) {
    const unsigned short* qsrc =
        Q + ((size_t)(b * SEQ + s0 + wave * 64 + qg * 16 + ln)) * 1024 + h * 64 + q8;
    qf[qg][0] = *(const short8*)qsrc;
    qf[qg][1] = *(const short8*)(qsrc + 32);
#pragma unroll
    for (int e = 0; e < 8; ++e) {
      qf[qg][0][e] = (short)f2bf(bf2f((unsigned short)qf[qg][0][e]) * qscale);
      qf[qg][1][e] = (short)f2bf(bf2f((unsigned short)qf[qg][1][e]) * qscale);
    }
  }

  // staging: chunk c = (wave*2+it)*64 + lane; LDS row=c>>3; gcc=(c&7)^(row&7)
  const int srow = lane >> 3;
  const int sgcc = (lane & 7) ^ srow;

  auto stage = [&](int t0, int p) {
#pragma unroll
    for (int it = 0; it < 2; ++it) {
      const int row = wave * 16 + it * 8 + srow;
      // sigma: key bit perm {r5,r3,r2,r4,r1,r0} -> QK out slots == PV A-frag
      const int skey = (row & 32) | ((row & 8) << 1) | ((row & 4) << 1) |
                       ((row & 16) >> 2) | (row & 3);
      async_copy16(Kb + (size_t)(b * SEQ + t0 + skey) * 256 + g * 64 + sgcc * 8,
                   &Ks[p][(wave * 2 + it) * 512]);
      async_copy16(Vt + (size_t)(b * 256 + g * 64 + row) * SEQ + t0 + sgcc * 8,
                   &Vs[p][(wave * 2 + it) * 512]);
    }
  };

  f32x4 of[4][4];
  f32x4 ls[4];
#pragma unroll
  for (int qg = 0; qg < 4; ++qg) {
    ls[qg] = (f32x4){0.f, 0.f, 0.f, 0.f};
#pragma unroll
    for (int jd = 0; jd < 4; ++jd) of[qg][jd] = (f32x4){0.f, 0.f, 0.f, 0.f};
  }

  const int tbase = half * 16;          // this half's first KV tile
  stage(tbase * 64, 0);                 // prologue prefetch (4 DMAs/wave)

  for (int tt = 0; tt < 16; ++tt) {
    const int p = tt & 1;
    if (tt < 15) {
      stage((tbase + tt + 1) * 64, p ^ 1);             // 4 new DMAs in flight
      asm volatile("s_waitcnt vmcnt(4)" ::: "memory"); // wait only tile-t DMAs
    } else {
      asm volatile("s_waitcnt vmcnt(0)" ::: "memory");
    }
    __builtin_amdgcn_s_barrier();                      // tile t fully in LDS
    asm volatile("" ::: "memory");

    // ---- QK^T + softmax in two qg-halves (live sc halved: 32 f32 not 64)
    short8 pf[4][2];
#pragma unroll
    for (int hf = 0; hf < 2; ++hf) {
      f32x4 sc[2][4];
#pragma unroll
      for (int jn = 0; jn < 4; ++jn) {
        const int krow = (jn * 16 + ln) * 64;
        const short8 kf0 = *(const short8*)&Ks[p][krow + x0];
        const short8 kf1 = *(const short8*)&Ks[p][krow + x1];
#pragma unroll
        for (int q2 = 0; q2 < 2; ++q2) {
          const int qg = hf * 2 + q2;
          f32x4 z = (f32x4){0.f, 0.f, 0.f, 0.f};
          z = __builtin_amdgcn_mfma_f32_16x16x32_bf16(kf0, qf[qg][0], z, 0, 0, 0);
          z = __builtin_amdgcn_mfma_f32_16x16x32_bf16(kf1, qf[qg][1], z, 0, 0, 0);
          sc[q2][jn] = z;
        }
      }
#pragma unroll
      for (int q2 = 0; q2 < 2; ++q2) {
        const int qg = hf * 2 + q2;
#pragma unroll
        for (int jn = 0; jn < 4; ++jn)
#pragma unroll
          for (int r = 0; r < 4; ++r) sc[q2][jn][r] = fexp2(sc[q2][jn][r]);
#pragma unroll
        for (int F = 0; F < 2; ++F) {
          union { unsigned u[4]; short8 s; } pk;
          pk.u[0] = cvt_pk_bf16(sc[q2][2 * F][0], sc[q2][2 * F][1]);
          pk.u[1] = cvt_pk_bf16(sc[q2][2 * F][2], sc[q2][2 * F][3]);
          pk.u[2] = cvt_pk_bf16(sc[q2][2 * F + 1][0], sc[q2][2 * F + 1][1]);
          pk.u[3] = cvt_pk_bf16(sc[q2][2 * F + 1][2], sc[q2][2 * F + 1][3]);
          pf[qg][F] = pk.s;
        }
        ls[qg] = __builtin_amdgcn_mfma_f32_16x16x32_bf16(pf[qg][0], ones, ls[qg], 0, 0, 0);
        ls[qg] = __builtin_amdgcn_mfma_f32_16x16x32_bf16(pf[qg][1], ones, ls[qg], 0, 0, 0);
      }
    }

    // ---- PV: vf frags shared by all 4 q-groups (natural key order)
#pragma unroll
    for (int jd = 0; jd < 4; ++jd) {
      const int vrow = (jd * 16 + ln) * 64;
      const short8 vf0 = *(const short8*)&Vs[p][vrow + x0];
      const short8 vf1 = *(const short8*)&Vs[p][vrow + x1];
#pragma unroll
      for (int qg = 0; qg < 4; ++qg) {
        of[qg][jd] = __builtin_amdgcn_mfma_f32_16x16x32_bf16(pf[qg][0], vf0, of[qg][jd], 0, 0, 0);
        of[qg][jd] = __builtin_amdgcn_mfma_f32_16x16x32_bf16(pf[qg][1], vf1, of[qg][jd], 0, 0, 0);
      }
    }

    asm volatile("" ::: "memory");
    __builtin_amdgcn_s_barrier();   // all buf-p reads done before t+1 overwrites
    asm volatile("" ::: "memory");
  }

  // ---- UNNORMALIZED packed numerator store + row-sum store
#pragma unroll
  for (int qg = 0; qg < 4; ++qg) {
    const int sbase = s0 + wave * 64 + qg * 16 + quad * 4;
    if (ln == 0) {  // lanes 0,16,32,48: ls for rows quad*4+r
#pragma unroll
      for (int r = 0; r < 4; ++r)
        lsO[(b * 16 + h) * 2048 + sbase + r] = ls[qg][r];
    }
#pragma unroll
    for (int jd = 0; jd < 4; ++jd) {
      const int d = jd * 16 + ln;
      ushort4 ov;
      ov.x = f2bf(of[qg][jd][0]);
      ov.y = f2bf(of[qg][jd][1]);
      ov.z = f2bf(of[qg][jd][2]);
      ov.w = f2bf(of[qg][jd][3]);
      *(ushort4*)&numO[((size_t)b * 1024 + h * 64 + d) * SEQ + sbase] = ov;
    }
  }
}

// ---------------------------------------------------------------------------
// Split-KV reduce: att = (num0 + att{=num1}) / (ls0 + ls1). In-place safe.
// ---------------------------------------------------------------------------
__global__ __launch_bounds__(256) void attn_reduce(
    const unsigned short* __restrict__ N0, unsigned short* att,
    const float* __restrict__ LS)
{
  const int i = (blockIdx.x * 256 + threadIdx.x) * 4;  // flat into [b][1024][2048]
  const int row = i >> 11, s = i & 2047;
  const int h = (row >> 6) & 15, b = row >> 10;
  const int lsi = (b * 16 + h) * 2048 + s;
  const float4 l0 = *(const float4*)&LS[lsi];
  const float4 l1 = *(const float4*)&LS[65536 + lsi];
  const ushort4 a = *(const ushort4*)&N0[i];
  const ushort4 c = *(const ushort4*)&att[i];
  ushort4 o;
  o.x = f2bf((bf2f(a.x) + bf2f(c.x)) / (l0.x + l1.x));
  o.y = f2bf((bf2f(a.y) + bf2f(c.y)) / (l0.y + l1.y));
  o.z = f2bf((bf2f(a.z) + bf2f(c.z)) / (l0.z + l1.z));
  o.w = f2bf((bf2f(a.w) + bf2f(c.w)) / (l0.w + l1.w));
  *(ushort4*)&att[i] = o;
}

// ---------------------------------------------------------------------------
// Residual + LayerNorm. One block per row (1024 cols), 256 thr x 4.
// ---------------------------------------------------------------------------
__device__ __forceinline__ void ln_core(float x[4], const float* gam, const float* bet,
                                        int tid, float out[4]) {
  float s1 = x[0] + x[1] + x[2] + x[3];
  float s2 = x[0] * x[0] + x[1] * x[1] + x[2] * x[2] + x[3] * x[3];
#pragma unroll
  for (int off = 1; off < 64; off <<= 1) {
    s1 += __shfl_xor(s1, off);
    s2 += __shfl_xor(s2, off);
  }
  __shared__ float r1[4], r2[4];
  const int wave = tid >> 6;
  if ((tid & 63) == 0) { r1[wave] = s1; r2[wave] = s2; }
  __syncthreads();
  s1 = r1[0] + r1[1] + r1[2] + r1[3];
  s2 = r2[0] + r2[1] + r2[2] + r2[3];
  const float mu  = s1 * (1.0f / HIDDEN);
  const float var = s2 * (1.0f / HIDDEN) - mu * mu;
  const float inv = rsqrtf(var + 1e-5f);
  float4 gv = *(const float4*)&gam[tid * 4];
  float4 bv = *(const float4*)&bet[tid * 4];
  out[0] = (x[0] - mu) * inv * gv.x + bv.x;
  out[1] = (x[1] - mu) * inv * gv.y + bv.y;
  out[2] = (x[2] - mu) * inv * gv.z + bv.z;
  out[3] = (x[3] - mu) * inv * gv.w + bv.w;
}

__global__ __launch_bounds__(256) void resid_ln1(
    const float* __restrict__ X, const unsigned short* __restrict__ Y,
    const float* __restrict__ gam, const float* __restrict__ bet,
    unsigned short* __restrict__ outb)
{
  const int row = blockIdx.x, tid = threadIdx.x;
  const size_t base = (size_t)row * HIDDEN + tid * 4;
  float4 a = *(const float4*)&X[base];
  ushort4 yv = *(const ushort4*)&Y[base];
  float x[4] = {a.x + bf2f(yv.x), a.y + bf2f(yv.y), a.z + bf2f(yv.z), a.w + bf2f(yv.w)};
  float o[4];
  ln_core(x, gam, bet, tid, o);
  ushort4 ov;
  ov.x = f2bf(o[0]); ov.y = f2bf(o[1]); ov.z = f2bf(o[2]); ov.w = f2bf(o[3]);
  *(ushort4*)&outb[base] = ov;
}

__global__ __launch_bounds__(256) void resid_ln2(
    const unsigned short* __restrict__ X, const unsigned short* __restrict__ Y,
    const float* __restrict__ gam, const float* __restrict__ bet,
    float* __restrict__ out)
{
  const int row = blockIdx.x, tid = threadIdx.x;
  const size_t base = (size_t)row * HIDDEN + tid * 4;
  ushort4 xv = *(const ushort4*)&X[base];
  ushort4 yv = *(const ushort4*)&Y[base];
  float x[4] = {bf2f(xv.x) + bf2f(yv.x), bf2f(xv.y) + bf2f(yv.y),
                bf2f(xv.z) + bf2f(yv.z), bf2f(xv.w) + bf2f(yv.w)};
  float o[4];
  ln_core(x, gam, bet, tid, o);
  float4 ov; ov.x = o[0]; ov.y = o[1]; ov.z = o[2]; ov.w = o[3];
  *(float4*)&out[base] = ov;
}

// ---------------------------------------------------------------------------
extern "C" void kernel_launch(void* const* d_in, const int* in_sizes, int n_in,
                              void* d_out, int out_size, void* d_ws, size_t ws_size,
                              hipStream_t stream)
{
  (void)in_sizes; (void)n_in; (void)out_size; (void)ws_size;
  const float* hs  = (const float*)d_in[0];
  const float* wq  = (const float*)d_in[1];
  const float* bq  = (const float*)d_in[2];
  const float* wk  = (const float*)d_in[3];
  const float* bk  = (const float*)d_in[4];
  const float* wv  = (const float*)d_in[5];
  const float* bvp = (const float*)d_in[6];
  const float* wo  = (const float*)d_in[7];
  const float* bo  = (const float*)d_in[8];
  const float* lng = (const float*)d_in[9];
  const float* lnb = (const float*)d_in[10];
  const float* w1  = (const float*)d_in[11];
  const float* b1  = (const float*)d_in[12];
  const float* w2  = (const float*)d_in[13];
  const float* b2  = (const float*)d_in[14];
  const float* flg = (const float*)d_in[15];
  const float* flb = (const float*)d_in[16];
  float* out = (float*)d_out;

  unsigned short* w = (unsigned short*)d_ws;
  unsigned short* wqb = w;                    // 1048576  (dead after gemm_qkv -> ls buf)
  unsigned short* wkb = w + 1048576;          //  262144
  unsigned short* wvb = w + 1310720;          //  262144
  unsigned short* wob = w + 1572864;          // 1048576
  unsigned short* w1b = w + 2621440;          // 1048576
  unsigned short* w2b = w + 3670016;          // 1048576
  unsigned short* hsb = w + 4718592;          // 4194304  (dead after gemm_qkv -> num0; reused: f1b)
  unsigned short* qb  = w + 8912896;          // 4194304  (reused: yb, f2b)
  unsigned short* kb  = w + 13107200;         // 1048576
  unsigned short* vt  = w + 14155776;         // 1048576
  unsigned short* att = w + 15204352;         // 4194304  (num1 -> reduced in place; reused: obb)
  unsigned short* f1b = hsb;
  unsigned short* yb  = qb;
  unsigned short* obb = att;
  unsigned short* f2b = qb;
  float* lsbuf = (float*)wqb;                 // 2 x 65536 f32 = 512 KB

  dim3 blk(256);
  cvt_all<<<dim3(8704), blk, 0, stream>>>(hs, wq, wk, wv, wo, w1, w2,
                                          hsb, wqb, wkb, wvb, wob, w1b, w2b);

  gemm_qkv<<<dim3(768), blk, 0, stream>>>(hsb, wqb, wkb, wvb, bq, bk, bvp,
                                          qb, kb, vt);
  attn_mfma<<<dim3(512), blk, 0, stream>>>(qb, kb, vt, hsb, att, lsbuf);
  attn_reduce<<<dim3(4096), blk, 0, stream>>>(hsb, att, lsbuf);
  gemm_wn<false><<<dim3(512), blk, 0, stream>>>(att, wob, bo, yb, 4096, 1024, 1024);
  resid_ln1<<<dim3(4096), blk, 0, stream>>>(hs, yb, lng, lnb, obb);
  gemm_wn<true><<<dim3(512), blk, 0, stream>>>(obb, w1b, b1, f1b, 4096, 1024, 1024);
  gemm_wn<false><<<dim3(512), blk, 0, stream>>>(f1b, w2b, b2, f2b, 4096, 1024, 1024);
  resid_ln2<<<dim3(4096), blk, 0, stream>>>(obb, f2b, flg, flb, out);
}